// Round 5
// baseline (96.730 us; speedup 1.0000x reference)
//
#include <hip/hip_runtime.h>
#include <hip/hip_bf16.h>

// Problem constants: B=64, N=32, S=256, D=128
#define B_SZ 64

typedef __attribute__((ext_vector_type(8))) short bf16x8;
typedef __attribute__((ext_vector_type(4))) float f32x4;

static __device__ __forceinline__ unsigned short f2bf(float f) {
    __hip_bfloat16 h = __float2bfloat16(f);
    return *reinterpret_cast<unsigned short*>(&h);
}

// Load 8 consecutive fp32 (32 B), convert to one bf16x8 fragment.
static __device__ __forceinline__ bf16x8 cvt_frag(const float* __restrict__ src) {
    float4 a = reinterpret_cast<const float4*>(src)[0];
    float4 b = reinterpret_cast<const float4*>(src)[1];
    union { bf16x8 v; unsigned short u[8]; } t;
    t.u[0] = f2bf(a.x); t.u[1] = f2bf(a.y); t.u[2] = f2bf(a.z); t.u[3] = f2bf(a.w);
    t.u[4] = f2bf(b.x); t.u[5] = f2bf(b.y); t.u[6] = f2bf(b.z); t.u[7] = f2bf(b.w);
    return t.v;
}

#define MFMA(A, Bv, C) __builtin_amdgcn_mfma_f32_16x16x32_bf16(A, Bv, C, 0, 0, 0)

// Single fused MaxSim megakernel: fp32->bf16 convert + B-in-register MFMA maxsim.
// wg < 512 (pos): x = wg&7 (XCD under default wg%8 placement), i = wg>>3;
//   column c = x*8 + (i&7) -> all 8 blocks of column c land on XCD x (doc reads
//   are 7/8 L2 hits). Block covers b in [ (i>>3)*8, +8 ).
// wg >= 512 (neg): pair b = wg-512, doc nd[b], single-b loop, score slot 64.
//
// Phase 1: block converts its OWN doc column: dense coalesced fp32 reads ->
//   XOR-swizzled 64 KiB LDS (a -> a ^ (((a>>8)&7)<<4) within each 16 KiB chunk,
//   same involution on write and read — the verified R4 cvt transform, kept
//   local). Each wave then loads its s-chunk's 16 B-fragments into registers.
// Phase 2: per batch b, all 256 threads stage q[b] into an 8 KiB frag-linear
//   LDS buffer (dense writes; reads dense per (kk,mt)); 32 MFMAs per wave;
//   row-max folded via shfl butterfly into wred.
// No DP/QP in global memory; no fences.
__global__ __launch_bounds__(256, 2) void maxsim_mega(const float* __restrict__ q,
                                                      const float* __restrict__ dd,
                                                      const float* __restrict__ nd,
                                                      float* __restrict__ scores) {
    const int wg  = blockIdx.x;
    const int tid = threadIdx.x;
    const int wave = tid >> 6, lane = tid & 63;
    const int l15 = lane & 15, lhi = lane >> 4;

    __shared__ bf16x8 docL[4096];        // 64 KiB, swizzled doc fragments
    __shared__ bf16x8 qL[512];           // 8 KiB, frag-linear q[b] fragments
    __shared__ float wred[8][4][4][8];   // [bi][wave][lhi][mt*4+r]

    int c, b0, nb;
    const float* docp;
    if (wg < 512) {
        const int x = wg & 7, i = wg >> 3;
        c   = x * 8 + (i & 7);
        b0  = (i >> 3) * 8;
        nb  = 8;
        docp = dd + (size_t)c * 32768;
    } else {
        b0 = wg - 512; c = 64; nb = 1;
        docp = nd + (size_t)b0 * 32768;
    }

    // ---- Phase 1: doc convert via swizzled LDS bounce ----
    char* lb = reinterpret_cast<char*>(docL);
    #pragma unroll
    for (int i = 0; i < 16; ++i) {
        const int rem_g = i * 256 + tid;         // octet index: s*16 + k8
        bf16x8 v = cvt_frag(docp + (size_t)rem_g * 8);
        const int ch = rem_g >> 10, rem = rem_g & 1023;
        const int a = ch * 16384 + ((rem * 16) ^ (((rem >> 4) & 7) << 4));
        *reinterpret_cast<bf16x8*>(lb + a) = v;
    }
    __syncthreads();

    // wave w's s-chunk (ch = wave) -> 16 B-fragments in registers
    bf16x8 Bv[4][4];                     // [kk][nt]
    #pragma unroll
    for (int kk = 0; kk < 4; ++kk)
        #pragma unroll
        for (int nt = 0; nt < 4; ++nt) {
            const int rem = (nt * 16 + l15) * 16 + kk * 4 + lhi;
            const int a = wave * 16384 + ((rem * 16) ^ (((rem >> 4) & 7) << 4));
            Bv[kk][nt] = *reinterpret_cast<const bf16x8*>(lb + a);
        }

    // ---- Phase 2: loop over batches ----
    for (int bi = 0; bi < nb; ++bi) {
        const int b = b0 + bi;
        // stage q[b] into qL, frag-linear: thread t computes frags t, t+256.
        // frag g = kk*128 + mt*64 + ln  <->  octet (n = mt*16+(ln&15),
        //                                          k8 = kk*4+(ln>>4))
        #pragma unroll
        for (int h = 0; h < 2; ++h) {
            const int g  = h * 256 + tid;
            const int n  = ((g >> 6) & 1) * 16 + (g & 15);
            const int k8 = (g >> 7) * 4 + ((g >> 4) & 3);
            qL[g] = cvt_frag(q + (size_t)b * 4096 + (size_t)(n * 16 + k8) * 8);
        }
        __syncthreads();

        bf16x8 Af[4][2];
        #pragma unroll
        for (int kk = 0; kk < 4; ++kk) {
            Af[kk][0] = qL[kk * 128 + lane];
            Af[kk][1] = qL[kk * 128 + 64 + lane];
        }
        f32x4 acc[2][4] = {};            // [mt][nt]
        #pragma unroll
        for (int kk = 0; kk < 4; ++kk)
            #pragma unroll
            for (int nt = 0; nt < 4; ++nt) {
                acc[0][nt] = MFMA(Af[kk][0], Bv[kk][nt], acc[0][nt]);
                acc[1][nt] = MFMA(Af[kk][1], Bv[kk][nt], acc[1][nt]);
            }
        // max over this wave's 64 docs; butterfly over l15 -> per-row chunk max
        #pragma unroll
        for (int mt = 0; mt < 2; ++mt)
            #pragma unroll
            for (int r = 0; r < 4; ++r) {
                float m = fmaxf(fmaxf(acc[mt][0][r], acc[mt][1][r]),
                                fmaxf(acc[mt][2][r], acc[mt][3][r]));
                m = fmaxf(m, __shfl_xor(m, 1, 64));
                m = fmaxf(m, __shfl_xor(m, 2, 64));
                m = fmaxf(m, __shfl_xor(m, 4, 64));
                m = fmaxf(m, __shfl_xor(m, 8, 64));
                if (l15 == 0) wred[bi][wave][lhi][mt * 4 + r] = m;
                // row n = mt*16 + lhi*4 + r
            }
        __syncthreads();                 // protect qL overwrite / final wred read
    }

    // ---- final: max over the 4 s-chunks, then sum over the 32 query rows ----
    if (tid < nb * 32) {
        const int bi = tid >> 5, n = tid & 31;
        const int slot = (n >> 4) * 4 + (n & 3);   // mt*4 + r
        const int lh   = (n >> 2) & 3;
        float m = fmaxf(fmaxf(wred[bi][0][lh][slot], wred[bi][1][lh][slot]),
                        fmaxf(wred[bi][2][lh][slot], wred[bi][3][lh][slot]));
        m += __shfl_xor(m, 1, 32);
        m += __shfl_xor(m, 2, 32);
        m += __shfl_xor(m, 4, 32);
        m += __shfl_xor(m, 8, 32);
        m += __shfl_xor(m, 16, 32);
        if (n == 0) scores[(size_t)(b0 + bi) * 65 + c] = m;  // c==64 -> neg slot
    }
}

static __device__ __forceinline__ float softplusf(float x) {
    return fmaxf(x, 0.0f) + log1pf(expf(-fabsf(x)));
}

__global__ __launch_bounds__(64) void loss_kernel(const float* __restrict__ scores,
                                                  float* __restrict__ out) {
    const int b = threadIdx.x;           // 64 threads = 1 wave
    const float* row = scores + b * 65;
    const float pos  = row[b];
    const float negq = row[64];
    float nib = -1e30f;
    #pragma unroll
    for (int c = 0; c < B_SZ; ++c) {
        float v = row[c] - ((c == b) ? 1000000.0f : 0.0f);
        nib = fmaxf(nib, v);
    }
    float t = softplusf(negq - pos) + softplusf(nib - pos);
    t += __shfl_xor(t, 1, 64);
    t += __shfl_xor(t, 2, 64);
    t += __shfl_xor(t, 4, 64);
    t += __shfl_xor(t, 8, 64);
    t += __shfl_xor(t, 16, 64);
    t += __shfl_xor(t, 32, 64);
    if (b == 0) out[0] = t * (0.5f / 64.0f);
}

extern "C" void kernel_launch(void* const* d_in, const int* in_sizes, int n_in,
                              void* d_out, int out_size, void* d_ws, size_t ws_size,
                              hipStream_t stream) {
    const float* q  = (const float*)d_in[0];   // (64, 32, 128)
    const float* dd = (const float*)d_in[1];   // (64, 256, 128)
    const float* nd = (const float*)d_in[2];   // (64, 256, 128)
    float* out = (float*)d_out;

    // Workspace: scores (64 x 65 f32) only.
    float* scores = (float*)d_ws;

    maxsim_mega<<<512 + B_SZ, 256, 0, stream>>>(q, dd, nd, scores);
    loss_kernel<<<1, 64, 0, stream>>>(scores, out);
}